// Round 12
// baseline (140.268 us; speedup 1.0000x reference)
//
#include <hip/hip_runtime.h>
#include <hip/hip_bf16.h>

#define Bsz 4
#define Ssz 2048
#define Dsz 512
#define Hsz 8
#define DKsz 64

typedef __bf16 bf16x8 __attribute__((ext_vector_type(8)));
typedef __bf16 bf16x4 __attribute__((ext_vector_type(4)));
typedef float f32x4 __attribute__((ext_vector_type(4)));
typedef unsigned u32x2 __attribute__((ext_vector_type(2)));
typedef unsigned u32x4 __attribute__((ext_vector_type(4)));

#if defined(__has_builtin)
#if __has_builtin(__builtin_amdgcn_permlane32_swap) && \
    __has_builtin(__builtin_amdgcn_permlane16_swap)
#define PERMLANE_OK 1
#endif
#endif
#ifndef PERMLANE_OK
#define PERMLANE_OK 0
#endif

// chunk-swizzled element offset: 16B chunk c of a 64-elem (128B) row, XOR row&7
#define SWE(c, row) ((((c) ^ ((row) & 7)) * 8))

// direct global->LDS 16B/lane copy (lane l writes lds_base + l*16)
#define GLL16(g, l) __builtin_amdgcn_global_load_lds(                      \
    (const __attribute__((address_space(1))) void*)(g),                    \
    (__attribute__((address_space(3))) void*)(l), 16, 0, 0)

// ---------------------------------------------------------------------------
// cvt: x (4.19M fp32) + Wq|Wk|Wv (3 x 262144 fp32) -> bf16 in ws.
// (R9: fusing into qkv regresses — fp32 staging doubles qkv L2/HBM bytes.)
__global__ __launch_bounds__(256) void cvt_kernel(
    const float* __restrict__ x, const float* __restrict__ Wq,
    const float* __restrict__ Wk, const float* __restrict__ Wv,
    __bf16* __restrict__ xb, __bf16* __restrict__ Wb)
{
    const int i = blockIdx.x * 256 + threadIdx.x;   // float4 index
    const int XN4 = (Bsz * Ssz * Dsz) / 4;          // 1,048,576
    const float* src;
    __bf16* dst;
    int off;
    if (i < XN4) {
        src = x; dst = xb; off = i;
    } else {
        int j = i - XN4;                             // 0 .. 196607
        int w = j >> 16;                             // 0,1,2
        off = j & 65535;
        src = (w == 0) ? Wq : (w == 1) ? Wk : Wv;
        dst = Wb + (size_t)w * (Dsz * Dsz);
    }
    float4 v = ((const float4*)src)[off];
    __bf16 o[4] = {(__bf16)v.x, (__bf16)v.y, (__bf16)v.z, (__bf16)v.w};
    *(uint2*)(dst + (size_t)off * 4) = *(uint2*)o;
}

// ---------------------------------------------------------------------------
// Fused qkv projection, L2-LOCALITY SWIZZLED grid (1-D, 768 blocks).
// Staging via global_load_lds width=16: LDS dest LINEAR, global source chunk
// PRE-XORed (rule #21). 128x128 tile, 2-barrier K-loop.  [verified R3-R11]
__global__ __launch_bounds__(256, 3) void qkv_kernel(
    const __bf16* __restrict__ xb, const __bf16* __restrict__ Wb,
    __bf16* __restrict__ Qo, __bf16* __restrict__ Ko, __bf16* __restrict__ Vo)
{
    __shared__ __bf16 xs[128][64];
    __shared__ __bf16 wsh[128][64];

    const int tid  = threadIdx.x;
    const int lane = tid & 63;
    const int wave = tid >> 6;
    const int quad = lane >> 4;
    const int l16  = lane & 15;
    const int wm   = (wave & 1) * 64;
    const int wn   = (wave >> 1) * 64;

    const int lin = blockIdx.x;
    const int xcd = lin & 7;
    const int idx = lin >> 3;             // 0..95
    const int tnw = idx % 12;             // fast per XCD: sweeps (tn, which)
    const int tmh = idx / 12;             // slow: x-tile group
    const int tm  = (tmh * 8 + xcd) * 128;
    const int tn  = (tnw & 3) * 128;
    const int which = tnw >> 2;           // 0=Q 1=K 2=V
    const bool VM = (which == 2);
    const __bf16* W = Wb + (size_t)which * (Dsz * Dsz);

    const int rl  = lane >> 3;            // 0..7
    const int gch = (lane & 7) ^ rl;      // pre-swizzled 16B chunk
    const __bf16* xsrc = xb + (size_t)(tm + wave * 8 + rl) * Dsz + gch * 8;
    const __bf16* wsrc = W  + (size_t)(tn + wave * 8 + rl) * Dsz + gch * 8;

    f32x4 acc[4][4];
    #pragma unroll
    for (int i = 0; i < 4; ++i)
        #pragma unroll
        for (int j = 0; j < 4; ++j) acc[i][j] = (f32x4){0.f, 0.f, 0.f, 0.f};

    const __bf16 (*Ash)[64] = VM ? xs : wsh;
    const __bf16 (*Bsh)[64] = VM ? wsh : xs;

    for (int k0 = 0; k0 < Dsz; k0 += 64) {
        __syncthreads();                  // previous tile fully consumed
        #pragma unroll
        for (int i = 0; i < 4; ++i) {
            GLL16(xsrc + (size_t)(32 * i) * Dsz + k0, &xs[wave * 8 + 32 * i][0]);
            GLL16(wsrc + (size_t)(32 * i) * Dsz + k0, &wsh[wave * 8 + 32 * i][0]);
        }
        asm volatile("s_waitcnt vmcnt(0)" ::: "memory");
        __syncthreads();

        #pragma unroll
        for (int kk = 0; kk < 2; ++kk) {
            bf16x8 fa[4], fb[4];
            #pragma unroll
            for (int mi = 0; mi < 4; ++mi) {
                const int row = wm + mi * 16 + l16;
                fa[mi] = *(const bf16x8*)&Ash[row][SWE(kk * 4 + quad, row)];
            }
            #pragma unroll
            for (int ni = 0; ni < 4; ++ni) {
                const int row = wn + ni * 16 + l16;
                fb[ni] = *(const bf16x8*)&Bsh[row][SWE(kk * 4 + quad, row)];
            }
            #pragma unroll
            for (int mi = 0; mi < 4; ++mi)
                #pragma unroll
                for (int ni = 0; ni < 4; ++ni)
                    acc[mi][ni] = __builtin_amdgcn_mfma_f32_16x16x32_bf16(
                        fa[mi], fb[ni], acc[mi][ni], 0, 0, 0);
        }
    }

    if (!VM) {
        const float scale = (which == 0) ? 0.125f * 1.44269504088896340736f : 1.0f;
        __bf16* dst = (which == 0) ? Qo : Ko;
        #pragma unroll
        for (int mi = 0; mi < 4; ++mi) {
            const int e0 = tn + wm + mi * 16 + quad * 4;
            const int h = e0 >> 6, d0 = e0 & 63;
            #pragma unroll
            for (int ni = 0; ni < 4; ++ni) {
                const int sf = tm + wn + ni * 16 + l16;
                const int b = sf >> 11, s = sf & (Ssz - 1);
                bf16x4 p;
                #pragma unroll
                for (int r = 0; r < 4; ++r) p[r] = (__bf16)(acc[mi][ni][r] * scale);
                *(bf16x4*)&dst[((((size_t)(b * Hsz + h) * Ssz + s)) << 6) + d0] = p;
            }
        }
    } else {
        #pragma unroll
        for (int mi = 0; mi < 4; ++mi) {
            const int sf0 = tm + wm + mi * 16 + quad * 4;
            const int b = sf0 >> 11, s0 = sf0 & (Ssz - 1);
            #pragma unroll
            for (int ni = 0; ni < 4; ++ni) {
                const int e = tn + wn + ni * 16 + l16;
                const int h = e >> 6, d = e & 63;
                bf16x4 p;
                #pragma unroll
                for (int r = 0; r < 4; ++r) p[r] = (__bf16)acc[mi][ni][r];
                *(bf16x4*)&Vo[(((size_t)(b * Hsz + h) * DKsz + d) << 11) + s0] = p;
            }
        }
    }
}

// ---------------------------------------------------------------------------
// Flash attention = R11 structure (triple-buffer, counted vmcnt(4), verified
// 49.0us) + IN-REGISTER P^T via permlane builtins (T12). R1's failure was
// the hand-rolled 2-instr asm block; the quarter-level mapping re-verified
// correct under LLVM-documented semantics:
//   pl32(a,b): a'={a0,a1,b0,b1} b'={a2,a3,b2,b3}   (quarters = 16-lane rows)
//   pl16(a,b): a''={a0,b0,a2,b2} b''={a1,b1,a3,b3}
// chain on (cpk[ns][p], cpk[ns+1][p]) yields af words {s=8Q+2w,+1} exactly.
// bf16 pairs packed PORTABLY (identical RTNE rounding to the passing path).
// #if-guard falls back to the verified ps-LDS path if builtins missing.
// Removes 64 b64 writes + 32 b128 reads (~640 LDS cyc/CU-tile of ~2400) and
// the pack->lgkm->read serialization; frees 16 KB LDS.
// Prediction check: SQ_LDS_BANK_CONFLICT 2^21 should drop to ~0 (ps was it).
__global__ __launch_bounds__(256, 2) void attn_kernel(
    const __bf16* __restrict__ Q, const __bf16* __restrict__ K,
    const __bf16* __restrict__ VT, float* __restrict__ out)
{
    __shared__ __bf16 ks[3][64][64];     // K[s_local][dk], swizzled chunks
    __shared__ __bf16 vs[3][64][64];     // V^T[dk][s_local], swizzled chunks
#if !PERMLANE_OK
    __shared__ __bf16 psA[4][16][64];    // fallback P^T buffers
    __shared__ __bf16 psB[4][16][64];
#endif

    const int tid  = threadIdx.x;
    const int lane = tid & 63;
    const int wave = tid >> 6;
    const int quad = lane >> 4;
    const int l16  = lane & 15;

    const int bh = blockIdx.x;           // all q-blocks of a bh share an XCD L2
    const int qt = blockIdx.y;           // 128-row q tile
    const int b  = bh >> 3;
    const int h  = bh & 7;

    const __bf16* Qb = Q  + (size_t)bh * Ssz * DKsz;
    const __bf16* Kb = K  + (size_t)bh * Ssz * DKsz;
    const __bf16* Vb = VT + (size_t)bh * DKsz * Ssz;

    // Q fragments: lane l16 = q-local row, quad*8 = dk chunk
    bf16x8 qf[2][2];
    #pragma unroll
    for (int qs = 0; qs < 2; ++qs) {
        const __bf16* qrow = Qb + (size_t)(qt * 128 + wave * 32 + qs * 16 + l16) * DKsz;
        qf[qs][0] = *(const bf16x8*)(qrow + quad * 8);
        qf[qs][1] = *(const bf16x8*)(qrow + 32 + quad * 8);
    }

    bf16x8 ones;
    #pragma unroll
    for (int i = 0; i < 8; ++i) ones[i] = (__bf16)1.0f;

    f32x4 oacc[2][4];
    #pragma unroll
    for (int qs = 0; qs < 2; ++qs)
        #pragma unroll
        for (int i = 0; i < 4; ++i) oacc[qs][i] = (f32x4){0.f, 0.f, 0.f, 0.f};
    f32x4 lacc[2] = {(f32x4){0.f, 0.f, 0.f, 0.f}, (f32x4){0.f, 0.f, 0.f, 0.f}};

    const int rl  = lane >> 3;
    const int gch = (lane & 7) ^ rl;     // pre-swizzled 16B chunk

#define STAGE_KV(DST, KBASE)                                                   \
    do {                                                                       \
        const __bf16* kgs = Kb + (size_t)((KBASE) + wave * 8 + rl) * DKsz      \
                               + gch * 8;                                      \
        const __bf16* vgs = Vb + (size_t)(wave * 8 + rl) * Ssz + (KBASE)       \
                               + gch * 8;                                      \
        GLL16(kgs,                        &ks[DST][wave * 8][0]);              \
        GLL16(kgs + (size_t)32 * DKsz,    &ks[DST][wave * 8 + 32][0]);         \
        GLL16(vgs,                        &vs[DST][wave * 8][0]);              \
        GLL16(vgs + (size_t)32 * Ssz,     &vs[DST][wave * 8 + 32][0]);         \
    } while (0)

#if PERMLANE_OK
// P->af redistribution fully in-register: for word-pair p, chain
// pl32 then pl16 on (cpk[ns],cpk[ns+1]); results are af words p and 2+p.
#define MAKE_AF(QS)                                                            \
    do {                                                                       \
        unsigned cpk[4][2];                                                    \
        _Pragma("unroll")                                                      \
        for (int ns = 0; ns < 4; ++ns)                                         \
            _Pragma("unroll")                                                  \
            for (int p = 0; p < 2; ++p) {                                      \
                union { __bf16 hh[2]; unsigned u; } t;                         \
                t.hh[0] = (__bf16)__builtin_amdgcn_exp2f(st[QS][ns][2 * p]);   \
                t.hh[1] = (__bf16)__builtin_amdgcn_exp2f(st[QS][ns][2 * p + 1]);\
                cpk[ns][p] = t.u;                                              \
            }                                                                  \
        u32x4 A0, A1;                                                          \
        _Pragma("unroll")                                                      \
        for (int p = 0; p < 2; ++p) {                                          \
            u32x2 r = __builtin_amdgcn_permlane32_swap(                        \
                cpk[0][p], cpk[1][p], false, false);                           \
            r = __builtin_amdgcn_permlane16_swap(r[0], r[1], false, false);    \
            A0[p] = r[0]; A0[2 + p] = r[1];                                    \
            r = __builtin_amdgcn_permlane32_swap(                              \
                cpk[2][p], cpk[3][p], false, false);                           \
            r = __builtin_amdgcn_permlane16_swap(r[0], r[1], false, false);    \
            A1[p] = r[0]; A1[2 + p] = r[1];                                    \
        }                                                                      \
        af[QS][0] = __builtin_bit_cast(bf16x8, A0);                            \
        af[QS][1] = __builtin_bit_cast(bf16x8, A1);                            \
    } while (0)
#else
#define MAKE_AF(QS)                                                            \
    do {                                                                       \
        _Pragma("unroll")                                                      \
        for (int ns = 0; ns < 4; ++ns) {                                       \
            bf16x4 pp;                                                         \
            _Pragma("unroll")                                                  \
            for (int r = 0; r < 4; ++r)                                        \
                pp[r] = (__bf16)__builtin_amdgcn_exp2f(st[QS][ns][r]);         \
            __bf16* pbase = (QS) ? &psB[wave][l16][0] : &psA[wave][l16][0];    \
            const int c = ns * 2 + (quad >> 1);                                \
            *(bf16x4*)&pbase[((c ^ (l16 & 7)) << 3) + ((quad & 1) << 2)] = pp; \
        }                                                                      \
        {                                                                      \
            const __bf16* pbase = (QS) ? &psB[wave][l16][0]                    \
                                       : &psA[wave][l16][0];                   \
            af[QS][0] = *(const bf16x8*)&pbase[SWE(quad, l16)];                \
            af[QS][1] = *(const bf16x8*)&pbase[SWE(4 + quad, l16)];            \
        }                                                                      \
    } while (0)
#endif

#define ATTN_COMPUTE(CUR)                                                      \
    do {                                                                       \
        bf16x8 kf[2][4], vf[2][4];                                             \
        _Pragma("unroll")                                                      \
        for (int kk = 0; kk < 2; ++kk)                                         \
            _Pragma("unroll")                                                  \
            for (int ns = 0; ns < 4; ++ns) {                                   \
                const int row = ns * 16 + l16;                                 \
                kf[kk][ns] = *(const bf16x8*)&ks[CUR][row][SWE(kk*4+quad,row)];\
                vf[kk][ns] = *(const bf16x8*)&vs[CUR][row][SWE(kk*4+quad,row)];\
            }                                                                  \
        __builtin_amdgcn_s_setprio(1);                                         \
        f32x4 st[2][4];                                                        \
        _Pragma("unroll")                                                      \
        for (int qs = 0; qs < 2; ++qs)                                         \
            _Pragma("unroll")                                                  \
            for (int ns = 0; ns < 4; ++ns) {                                   \
                f32x4 t = (f32x4){0.f, 0.f, 0.f, 0.f};                         \
                t = __builtin_amdgcn_mfma_f32_16x16x32_bf16(                   \
                        kf[0][ns], qf[qs][0], t, 0, 0, 0);                     \
                t = __builtin_amdgcn_mfma_f32_16x16x32_bf16(                   \
                        kf[1][ns], qf[qs][1], t, 0, 0, 0);                     \
                st[qs][ns] = t;                                                \
            }                                                                  \
        __builtin_amdgcn_s_setprio(0);                                         \
        bf16x8 af[2][2];                                                       \
        MAKE_AF(0);                                                            \
        MAKE_AF(1);                                                            \
        __builtin_amdgcn_s_setprio(1);                                         \
        _Pragma("unroll")                                                      \
        for (int qs = 0; qs < 2; ++qs) {                                       \
            _Pragma("unroll")                                                  \
            for (int ns = 0; ns < 4; ++ns) {                                   \
                oacc[qs][ns] = __builtin_amdgcn_mfma_f32_16x16x32_bf16(        \
                    vf[0][ns], af[qs][0], oacc[qs][ns], 0, 0, 0);              \
                oacc[qs][ns] = __builtin_amdgcn_mfma_f32_16x16x32_bf16(        \
                    vf[1][ns], af[qs][1], oacc[qs][ns], 0, 0, 0);              \
            }                                                                  \
            lacc[qs] = __builtin_amdgcn_mfma_f32_16x16x32_bf16(                \
                ones, af[qs][0], lacc[qs], 0, 0, 0);                           \
            lacc[qs] = __builtin_amdgcn_mfma_f32_16x16x32_bf16(                \
                ones, af[qs][1], lacc[qs], 0, 0, 0);                           \
        }                                                                      \
        __builtin_amdgcn_s_setprio(0);                                         \
    } while (0)

    // prologue: stage tiles 0,1; drain ALL vmem (incl. Q loads -> in-loop
    // vmcnt counting starts from a clean 0); publish.
    STAGE_KV(0, 0);
    STAGE_KV(1, 64);
    asm volatile("s_waitcnt vmcnt(0)\n\ts_barrier" ::: "memory");

    // main loop: tile T issues stage(T+2) -> outstanding 8; compute(T);
    // trailing vmcnt(4) waits stage(T+1) only (FIFO), leaving stage(T+2)
    // in flight across the barrier.
    int cur = 0;
    for (int t = 0; t < 30; ++t) {
        const int nx2 = (cur == 0) ? 2 : cur - 1;   // (t+2)%3
        STAGE_KV(nx2, t * 64 + 128);
        ATTN_COMPUTE(cur);
        asm volatile("s_waitcnt vmcnt(4) lgkmcnt(0)\n\ts_barrier" ::: "memory");
        cur = (cur == 2) ? 0 : cur + 1;
    }
    ATTN_COMPUTE(cur);
    asm volatile("s_waitcnt vmcnt(0) lgkmcnt(0)\n\ts_barrier" ::: "memory");
    cur = (cur == 2) ? 0 : cur + 1;
    ATTN_COMPUTE(cur);

    // epilogue: per-lane row-sum (col=q=l16), f32x4 stores along d
    #pragma unroll
    for (int qs = 0; qs < 2; ++qs) {
        const float linv = 1.f / (lacc[qs][0] + 1e-8f);
        const int q = qt * 128 + wave * 32 + qs * 16 + l16;
        float* obase = out + ((size_t)b * Ssz + q) * Dsz + h * DKsz;
        #pragma unroll
        for (int ns = 0; ns < 4; ++ns) {
            f32x4 o = oacc[qs][ns] * linv;
            *(f32x4*)(obase + ns * 16 + quad * 4) = o;
        }
    }
#undef ATTN_COMPUTE
#undef MAKE_AF
#undef STAGE_KV
}

extern "C" void kernel_launch(void* const* d_in, const int* in_sizes, int n_in,
                              void* d_out, int out_size, void* d_ws, size_t ws_size,
                              hipStream_t stream) {
    const float* x  = (const float*)d_in[0];
    const float* Wq = (const float*)d_in[1];
    const float* Wk = (const float*)d_in[2];
    const float* Wv = (const float*)d_in[3];
    float* out = (float*)d_out;

    const size_t per = (size_t)Bsz * Hsz * Ssz * DKsz;  // 4,194,304 elems
    __bf16* Qw  = (__bf16*)d_ws;
    __bf16* Kw  = Qw + per;
    __bf16* VTw = Kw + per;
    __bf16* xb  = VTw + per;
    __bf16* Wb  = xb + per;                              // 786,432 elems

    cvt_kernel<<<4864, 256, 0, stream>>>(x, Wq, Wk, Wv, xb, Wb);
    qkv_kernel<<<768, 256, 0, stream>>>(xb, Wb, Qw, Kw, VTw);
    attn_kernel<<<dim3(Bsz * Hsz, Ssz / 128), 256, 0, stream>>>(Qw, Kw, VTw, out);
}